// Round 1
// baseline (443.005 us; speedup 1.0000x reference)
//
#include <hip/hip_runtime.h>
#include <cstdint>
#include <cstddef>

typedef unsigned short u16;
typedef unsigned int u32;
typedef __bf16 bf16x8 __attribute__((ext_vector_type(8)));
typedef float f32x4 __attribute__((ext_vector_type(4)));

#define SL 2048            // sequence length
#define NCH 8192           // B(16) * BIDIR(2) * N_OUT(256)
#define SEGS 64
#define SEGLEN 32

// out buffer element offsets (f32 output)
#define OFF_C2S 16777216
#define OFF_C1F 33554432
#define OFF_C2F 33562624
#define OFF_DF  33570816

__device__ __forceinline__ float bf2f(u16 u) {
  union { u32 i; float f; } v; v.i = ((u32)u) << 16; return v.f;
}
__device__ __forceinline__ u16 f2bf(float f) {
  union { float f; u32 i; } v; v.f = f;
  u32 x = v.i;
  return (u16)((x + 0x7fffu + ((x >> 16) & 1u)) >> 16);
}
// pack two f32 -> two bf16 (RNE), 1 VALU op instead of ~8
__device__ __forceinline__ u32 cvtpk(float lo, float hi) {
  u32 r;
  asm("v_cvt_pk_bf16_f32 %0, %1, %2" : "=v"(r) : "v"(lo), "v"(hi));
  return r;
}

// -------------------------------------------------------------------------
// Repack weight_in (f32, 256 x 3072, col = dir*1536 + n*6 + k) into bf16
// Wt[plane][ch2][kk]  (5 x 512 x 256, K-major) for contiguous GEMM B loads.
__global__ __launch_bounds__(256) void repack_kernel(
    const float* __restrict__ W, u16* __restrict__ Wt) {
  int idx = blockIdx.x * 256 + threadIdx.x;   // < 5*512*256 = 655360
  int kk = idx & 255;
  int rest = idx >> 8;
  int ch2 = rest & 511;
  int p = rest >> 9;
  Wt[idx] = f2bf(W[(size_t)kk * 3072 + (ch2 >> 8) * 1536 + (ch2 & 255) * 6 + p]);
}

// -------------------------------------------------------------------------
// MFMA GEMM over one flipped-time chunk [t0c, t0c+CHT). Block: 64 rows x 128
// cols; blockIdx.y = column tile (0..3) -> dir = tile>=2. A rows read from
// mirrored original time for dir=1, so buf is dense in flipped time.
// B fragments are loaded DIRECTLY from global Wt (1.31 MB, L2-resident) in
// MFMA fragment layout -- no Bs LDS staging, no per-kt barriers. Exactly one
// __syncthreads() per block (after A staging).
__global__ __launch_bounds__(256) void gemm_kernel(
    const float* __restrict__ x, const u16* __restrict__ Wt,
    const float* __restrict__ bias, u16* __restrict__ buf,
    u16* __restrict__ X2B, int t0c, int CHT) {
  __shared__ __align__(16) u16 As[2048 * 8];   // 32 KB
  const int tid = threadIdx.x;
  const int lane = tid & 63;
  const int wave = tid >> 6;
  const int wr = wave >> 1, wc = wave & 1;
  const int l15 = lane & 15, l4 = lane >> 4;
  const int rt = blockIdx.x;          // row tile within chunk (64 rows)
  const int ch0 = blockIdx.y * 128;   // 0,128,256,384
  const int dir = ch0 >> 8;           // 0 or 1

  // stage A strip (64 rows x 256 k): chunk = kb*64 + m, 8 elems each
#pragma unroll
  for (int i = 0; i < 8; ++i) {
    int chunk = tid + i * 256;
    int kb = chunk >> 6, m = chunk & 63;
    int tf = t0c + rt * 4 + (m >> 4);
    int ot = dir ? (SL - 1 - tf) : tf;
    int row = ot * 16 + (m & 15);
    const float* src = x + (size_t)row * 256 + kb * 8;
    f32x4 a = *(const f32x4*)src;
    f32x4 b = *(const f32x4*)(src + 4);
    union { bf16x8 v; u32 u[4]; } h;
    h.u[0] = cvtpk(a[0], a[1]);
    h.u[1] = cvtpk(a[2], a[3]);
    h.u[2] = cvtpk(b[0], b[1]);
    h.u[3] = cvtpk(b[2], b[3]);
    *(bf16x8*)(As + (size_t)chunk * 8) = h.v;
  }
  __syncthreads();   // As visible to all waves; As is read-only afterwards

  const size_t pstride = (size_t)CHT * NCH;
  for (int p = 0; p < 5; ++p) {
    f32x4 acc[2][4];
#pragma unroll
    for (int i = 0; i < 2; ++i)
#pragma unroll
      for (int j = 0; j < 4; ++j) acc[i][j] = (f32x4){0.f, 0.f, 0.f, 0.f};

    // per-lane B base row for this plane: ch2 = ch0 + wc*64 + j*16 + l15
    const u16* Wp = Wt + (size_t)(p * 512 + ch0 + wc * 64 + l15) * 256;

#pragma unroll
    for (int kt = 0; kt < 4; ++kt) {
#pragma unroll
      for (int h = 0; h < 2; ++h) {
        const int kb = kt * 8 + h * 4 + l4;
        bf16x8 bfr[4];
#pragma unroll
        for (int j = 0; j < 4; ++j)
          bfr[j] = *(const bf16x8*)(Wp + (size_t)j * 16 * 256 + kb * 8);
        bf16x8 af[2];
#pragma unroll
        for (int i = 0; i < 2; ++i)
          af[i] = *(const bf16x8*)(
              As + (size_t)(kb * 64 + wr * 32 + i * 16 + l15) * 8);
#pragma unroll
        for (int i = 0; i < 2; ++i)
#pragma unroll
          for (int j = 0; j < 4; ++j)
            acc[i][j] = __builtin_amdgcn_mfma_f32_16x16x32_bf16(
                af[i], bfr[j], acc[i][j], 0, 0, 0);
      }
    }

    // epilogue
    u16* pl = buf + (size_t)p * pstride;
#pragma unroll
    for (int j = 0; j < 4; ++j) {
      int ch2 = ch0 + wc * 64 + j * 16 + l15;
      float bv = (p >= 3) ? bias[p * 512 + ch2] : 0.f;
#pragma unroll
      for (int i = 0; i < 2; ++i) {
        int tl = rt * 4 + wr * 2 + i;     // row>>4 == wr*2+i
        int tf = t0c + tl;
        bool rec = (p == 1) && ((tf & 31) == 31);
#pragma unroll
        for (int r = 0; r < 4; r += 2) {
          float va = acc[i][j][r], vb = acc[i][j][r + 1];
          if (p >= 3) {
            va = 1.f / (1.f + __expf(-(va + bv)));
            vb = 1.f / (1.f + __expf(-(vb + bv)));
          }
          u32 pk = cvtpk(va, vb);
          int b = l4 * 4 + r;             // row&15
          int ch = b * 512 + ch2;
          size_t o = (size_t)tl * NCH + ch;
          pl[o] = (u16)pk;
          pl[o + 512] = (u16)(pk >> 16);  // b+1 -> ch+512
          if (rec) {
            size_t xo = (size_t)(tf >> 5) * NCH + ch;
            X2B[xo] = (u16)pk;
            X2B[xo + 512] = (u16)(pk >> 16);
          }
        }
      }
    }
  }
}

// -------------------------------------------------------------------------
// Pass A (per chunk): per (channel, segment) affine summary for both
// recurrences. 8 channels per thread -> bf16x8 (16B/lane) coalesced loads.
__global__ __launch_bounds__(256) void scanA_kernel(
    const u16* __restrict__ buf, const float* __restrict__ d_init,
    const u16* __restrict__ X2B,
    float* __restrict__ A1, float* __restrict__ B1,
    float* __restrict__ A2, float* __restrict__ B2, int c, int CHT) {
  int bid = blockIdx.x;               // (CHT/32) * 4 blocks
  int sl = bid >> 2, chb = bid & 3;
  int ch = chb * 2048 + threadIdx.x * 8;
  int s = c * (CHT / 32) + sl;        // global segment
  size_t pstride = (size_t)CHT * NCH;
  const u16* p0 = buf + (size_t)(sl * 32) * NCH + ch;

  float x2p[8];
  if (s == 0) {
    f32x4 d0 = *(const f32x4*)(d_init + ch);
    f32x4 d1 = *(const f32x4*)(d_init + ch + 4);
#pragma unroll
    for (int r = 0; r < 4; ++r) { x2p[r] = d0[r]; x2p[4 + r] = d1[r]; }
  } else {
    union { bf16x8 v; u16 s[8]; } xv;
    xv.v = *(const bf16x8*)(X2B + (size_t)(s - 1) * NCH + ch);
#pragma unroll
    for (int r = 0; r < 8; ++r) x2p[r] = bf2f(xv.s[r]);
  }

  float a1[8], b1[8], a2[8], b2[8];
#pragma unroll
  for (int r = 0; r < 8; ++r) { a1[r] = 1.f; b1[r] = 0.f; a2[r] = 1.f; b2[r] = 0.f; }

#pragma unroll 4
  for (int tt = 0; tt < SEGLEN; ++tt) {
    size_t off = (size_t)tt * NCH;
    union U { bf16x8 v; u16 s[8]; } v0, v1, v2, v3, v4;
    v0.v = *(const bf16x8*)(p0 + off);
    v1.v = *(const bf16x8*)(p0 + pstride + off);
    v2.v = *(const bf16x8*)(p0 + 2 * pstride + off);
    v3.v = *(const bf16x8*)(p0 + 3 * pstride + off);
    v4.v = *(const bf16x8*)(p0 + 4 * pstride + off);
#pragma unroll
    for (int r = 0; r < 8; ++r) {
      float x1 = bf2f(v0.s[r]), x2 = bf2f(v1.s[r]), x3 = bf2f(v2.s[r]);
      float f1 = bf2f(v3.s[r]), f2 = bf2f(v4.s[r]);
      a1[r] *= f1; b1[r] = f1 * b1[r] + (1.f - f1) * x1;
      float tmp = x3 * x2p[r];
      a2[r] *= f2; b2[r] = f2 * b2[r] + (1.f - f2) * tmp;
      x2p[r] = x2;
    }
  }
  size_t o = (size_t)s * NCH + ch;
  *(f32x4*)(A1 + o) = (f32x4){a1[0], a1[1], a1[2], a1[3]};
  *(f32x4*)(A1 + o + 4) = (f32x4){a1[4], a1[5], a1[6], a1[7]};
  *(f32x4*)(B1 + o) = (f32x4){b1[0], b1[1], b1[2], b1[3]};
  *(f32x4*)(B1 + o + 4) = (f32x4){b1[4], b1[5], b1[6], b1[7]};
  *(f32x4*)(A2 + o) = (f32x4){a2[0], a2[1], a2[2], a2[3]};
  *(f32x4*)(A2 + o + 4) = (f32x4){a2[4], a2[5], a2[6], a2[7]};
  *(f32x4*)(B2 + o) = (f32x4){b2[0], b2[1], b2[2], b2[3]};
  *(f32x4*)(B2 + o + 4) = (f32x4){b2[4], b2[5], b2[6], b2[7]};
}

// -------------------------------------------------------------------------
// Pass B: compose the 64 segment maps per channel -> carry-in per segment,
// plus final states (c1_f, c2_f, d_f) directly into out (f32).
__global__ __launch_bounds__(256) void scanB_kernel(
    const float* __restrict__ A1, const float* __restrict__ B1,
    const float* __restrict__ A2, const float* __restrict__ B2,
    const float* __restrict__ c1_init, const float* __restrict__ c2_init,
    const u16* __restrict__ X2B,
    float* __restrict__ C1c, float* __restrict__ C2c, float* __restrict__ out) {
  int ch = blockIdx.x * 256 + threadIdx.x;  // < 8192
  float c1 = c1_init[ch], c2 = c2_init[ch];
#pragma unroll 8
  for (int s = 0; s < SEGS; ++s) {
    int o = s * NCH + ch;
    C1c[o] = c1; C2c[o] = c2;
    c1 = A1[o] * c1 + B1[o];
    c2 = A2[o] * c2 + B2[o];
  }
  out[OFF_C1F + ch] = c1;
  out[OFF_C2F + ch] = c2;
  // d_f = x2 (flipped domain) at t = 2047 = segment-boundary slot 63
  out[OFF_DF + ch] = bf2f(X2B[(size_t)63 * NCH + ch]);
}

// -------------------------------------------------------------------------
// Pass C (per chunk): replay with known carries, write c1s/c2s as f32
// (un-flip dir=1 on store). 8 channels per thread, vectorized loads/stores.
__global__ __launch_bounds__(256) void scanC_kernel(
    const u16* __restrict__ buf, const float* __restrict__ d_init,
    const u16* __restrict__ X2B,
    const float* __restrict__ C1c, const float* __restrict__ C2c,
    float* __restrict__ out, int c, int CHT) {
  int bid = blockIdx.x;
  int sl = bid >> 2, chb = bid & 3;
  int ch = chb * 2048 + threadIdx.x * 8;
  int s = c * (CHT / 32) + sl;
  size_t pstride = (size_t)CHT * NCH;
  const u16* p0 = buf + (size_t)(sl * 32) * NCH + ch;
  int dir = (ch >> 8) & 1;    // uniform across the thread's 8 channels

  float x2p[8];
  if (s == 0) {
    f32x4 d0 = *(const f32x4*)(d_init + ch);
    f32x4 d1 = *(const f32x4*)(d_init + ch + 4);
#pragma unroll
    for (int r = 0; r < 4; ++r) { x2p[r] = d0[r]; x2p[4 + r] = d1[r]; }
  } else {
    union { bf16x8 v; u16 s[8]; } xv;
    xv.v = *(const bf16x8*)(X2B + (size_t)(s - 1) * NCH + ch);
#pragma unroll
    for (int r = 0; r < 8; ++r) x2p[r] = bf2f(xv.s[r]);
  }

  float c1[8], c2[8];
  {
    size_t o = (size_t)s * NCH + ch;
    f32x4 u0 = *(const f32x4*)(C1c + o);
    f32x4 u1 = *(const f32x4*)(C1c + o + 4);
    f32x4 w0 = *(const f32x4*)(C2c + o);
    f32x4 w1 = *(const f32x4*)(C2c + o + 4);
#pragma unroll
    for (int r = 0; r < 4; ++r) {
      c1[r] = u0[r]; c1[4 + r] = u1[r];
      c2[r] = w0[r]; c2[4 + r] = w1[r];
    }
  }

#pragma unroll 2
  for (int tt = 0; tt < SEGLEN; ++tt) {
    size_t off = (size_t)tt * NCH;
    union U { bf16x8 v; u16 s[8]; } v0, v1, v2, v3, v4;
    v0.v = *(const bf16x8*)(p0 + off);
    v1.v = *(const bf16x8*)(p0 + pstride + off);
    v2.v = *(const bf16x8*)(p0 + 2 * pstride + off);
    v3.v = *(const bf16x8*)(p0 + 3 * pstride + off);
    v4.v = *(const bf16x8*)(p0 + 4 * pstride + off);
#pragma unroll
    for (int r = 0; r < 8; ++r) {
      float x1 = bf2f(v0.s[r]), x2 = bf2f(v1.s[r]), x3 = bf2f(v2.s[r]);
      float f1 = bf2f(v3.s[r]), f2 = bf2f(v4.s[r]);
      c1[r] = f1 * c1[r] + (1.f - f1) * x1;
      float tmp = x3 * x2p[r];
      c2[r] = f2 * c2[r] + (1.f - f2) * tmp;
      x2p[r] = x2;
    }
    int tfl = s * 32 + tt;
    int t_out = dir ? (SL - 1 - tfl) : tfl;
    float* o1 = out + (size_t)t_out * NCH + ch;
    *(f32x4*)o1       = (f32x4){c1[0], c1[1], c1[2], c1[3]};
    *(f32x4*)(o1 + 4) = (f32x4){c1[4], c1[5], c1[6], c1[7]};
    float* o2 = o1 + OFF_C2S;
    *(f32x4*)o2       = (f32x4){c2[0], c2[1], c2[2], c2[3]};
    *(f32x4*)(o2 + 4) = (f32x4){c2[4], c2[5], c2[6], c2[7]};
  }
}

// -------------------------------------------------------------------------
extern "C" void kernel_launch(void* const* d_in, const int* in_sizes, int n_in,
                              void* d_out, int out_size, void* d_ws, size_t ws_size,
                              hipStream_t stream) {
  const float* x    = (const float*)d_in[0];   // (2048,16,256) f32
  const float* W    = (const float*)d_in[1];   // (256,3072) f32
  const float* bias = (const float*)d_in[2];   // (3072,) f32
  const float* c1i  = (const float*)d_in[3];   // (16,512) f32
  const float* c2i  = (const float*)d_in[4];
  const float* di   = (const float*)d_in[5];
  float* out = (float*)d_out;                  // f32 output (ref dtype)

  uint8_t* w8 = (uint8_t*)d_ws;
  u16* Wt  = (u16*)w8;                              // 1,310,720 B
  u16* X2B = (u16*)(w8 + 1310720ull);               // 1,048,576 B
  float* A1  = (float*)(w8 + 2359296ull);           // 6 x 2,097,152 B
  float* B1  = A1 + SEGS * NCH;
  float* A2  = B1 + SEGS * NCH;
  float* B2  = A2 + SEGS * NCH;
  float* C1c = B2 + SEGS * NCH;
  float* C2c = C1c + SEGS * NCH;
  const size_t FIXED = 2359296ull + 6ull * 2097152ull;  // 14,942,208 B
  u16* buf = (u16*)(w8 + FIXED);

  // pick the least chunking that fits ws_size (call-invariant)
  int NCHUNK = 64;
  size_t avail = (ws_size > FIXED) ? (ws_size - FIXED) : 0;
  for (int nc = 1; nc <= 64; nc <<= 1) {
    size_t need = (size_t)5 * (SL / nc) * NCH * 2;
    if (need <= avail) { NCHUNK = nc; break; }
  }
  const int CHT = SL / NCHUNK;

  hipLaunchKernelGGL(repack_kernel, dim3(2560), dim3(256), 0, stream, W, Wt);
  for (int c = 0; c < NCHUNK; ++c) {
    hipLaunchKernelGGL(gemm_kernel, dim3(CHT / 4, 4), dim3(256), 0, stream,
                       x, Wt, bias, buf, X2B, c * CHT, CHT);
    hipLaunchKernelGGL(scanA_kernel, dim3((CHT / 32) * 4), dim3(256), 0, stream,
                       buf, di, X2B, A1, B1, A2, B2, c, CHT);
  }
  hipLaunchKernelGGL(scanB_kernel, dim3(32), dim3(256), 0, stream,
                     A1, B1, A2, B2, c1i, c2i, X2B, C1c, C2c, out);
  for (int c = 0; c < NCHUNK; ++c) {
    if (NCHUNK > 1)
      hipLaunchKernelGGL(gemm_kernel, dim3(CHT / 4, 4), dim3(256), 0, stream,
                         x, Wt, bias, buf, X2B, c * CHT, CHT);
    hipLaunchKernelGGL(scanC_kernel, dim3((CHT / 32) * 4), dim3(256), 0, stream,
                       buf, di, X2B, C1c, C2c, out, c, CHT);
  }
}

// Round 2
// 310.189 us; speedup vs baseline: 1.4282x; 1.4282x over previous
//
#include <hip/hip_runtime.h>
#include <cstdint>
#include <cstddef>

typedef unsigned short u16;
typedef unsigned int u32;
typedef __bf16 bf16x8 __attribute__((ext_vector_type(8)));
typedef __bf16 bf16x4v __attribute__((ext_vector_type(4)));
typedef float f32x4 __attribute__((ext_vector_type(4)));

#define SL 2048            // sequence length
#define NCH 8192           // B(16) * BIDIR(2) * N_OUT(256)
#define SEGS 64
#define SEGLEN 32

// out buffer element offsets (f32 output)
#define OFF_C2S 16777216
#define OFF_C1F 33554432
#define OFF_C2F 33562624
#define OFF_DF  33570816

__device__ __forceinline__ float bf2f(u16 u) {
  union { u32 i; float f; } v; v.i = ((u32)u) << 16; return v.f;
}
__device__ __forceinline__ u16 f2bf(float f) {
  union { float f; u32 i; } v; v.f = f;
  u32 x = v.i;
  return (u16)((x + 0x7fffu + ((x >> 16) & 1u)) >> 16);
}
// pack two f32 -> two bf16 (RNE), 1 VALU op
__device__ __forceinline__ u32 cvtpk(float lo, float hi) {
  u32 r;
  asm("v_cvt_pk_bf16_f32 %0, %1, %2" : "=v"(r) : "v"(lo), "v"(hi));
  return r;
}

// -------------------------------------------------------------------------
// Repack weight_in (f32, 256 x 3072, col = dir*1536 + n*6 + k) into bf16 in
// MFMA-FRAGMENT order so gemm B loads are wave-contiguous 1KB:
//   flat = [p(5)][ct(4)][kt(4)][h(2)][wc(4)][j(2)][l4(4)][l15(16)][kk8(8)]
//   ch2 = ct*128 + wc*32 + j*16 + l15 ;  kk = (kt*8 + h*4 + l4)*8 + kk8
__global__ __launch_bounds__(256) void repack_kernel(
    const float* __restrict__ W, u16* __restrict__ Wt) {
  int idx = blockIdx.x * 256 + threadIdx.x;   // < 5*512*256 = 655360
  int kk8 = idx & 7;
  int l15 = (idx >> 3) & 15;
  int l4  = (idx >> 7) & 3;
  int j   = (idx >> 9) & 1;
  int wc  = (idx >> 10) & 3;
  int h   = (idx >> 12) & 1;
  int kt  = (idx >> 13) & 3;
  int ct  = (idx >> 15) & 3;
  int p   = idx >> 17;
  int ch2 = ct * 128 + wc * 32 + j * 16 + l15;
  int kk  = (kt * 8 + h * 4 + l4) * 8 + kk8;
  Wt[idx] = f2bf(W[(size_t)kk * 3072 + (ch2 >> 8) * 1536 + (ch2 & 255) * 6 + p]);
}

// -------------------------------------------------------------------------
// MFMA GEMM over one flipped-time chunk. Block: 64 rows x 128 cols;
// blockIdx.y = column tile ct (0..3) -> dir = ct>=2. Wave w = column quarter
// (wc = w): each wave computes all 64 rows x 32 cols, so every B element is
// loaded exactly once per block, as a fully-coalesced 1KB wave load from the
// fragment-ordered Wt (L2-resident). A staged once in LDS; ONE barrier total.
__global__ __launch_bounds__(256) void gemm_kernel(
    const float* __restrict__ x, const u16* __restrict__ Wt,
    const float* __restrict__ bias, u16* __restrict__ buf,
    u16* __restrict__ X2B, int t0c, int CHT) {
  __shared__ __align__(16) u16 As[2048 * 8];   // 32 KB
  const int tid = threadIdx.x;
  const int lane = tid & 63;
  const int wc = tid >> 6;            // wave = column quarter 0..3
  const int l15 = lane & 15, l4 = lane >> 4;
  const int rt = blockIdx.x;          // row tile within chunk (64 rows)
  const int ct = blockIdx.y;          // 0..3
  const int ch0 = ct * 128;
  const int dir = ch0 >> 8;           // 0 or 1

  // stage A strip (64 rows x 256 k): chunk = kb*64 + m, 8 elems each.
  // m-consecutive lanes -> conflict-free LDS writes (16B stride-1).
#pragma unroll
  for (int i = 0; i < 8; ++i) {
    int chunk = tid + i * 256;
    int kb = chunk >> 6, m = chunk & 63;
    int tf = t0c + rt * 4 + (m >> 4);
    int ot = dir ? (SL - 1 - tf) : tf;
    int row = ot * 16 + (m & 15);
    const float* src = x + (size_t)row * 256 + kb * 8;
    f32x4 a = *(const f32x4*)src;
    f32x4 b = *(const f32x4*)(src + 4);
    union { bf16x8 v; u32 u[4]; } hh;
    hh.u[0] = cvtpk(a[0], a[1]);
    hh.u[1] = cvtpk(a[2], a[3]);
    hh.u[2] = cvtpk(b[0], b[1]);
    hh.u[3] = cvtpk(b[2], b[3]);
    *(bf16x8*)(As + (size_t)chunk * 8) = hh.v;
  }
  __syncthreads();   // As visible; read-only afterwards

  const size_t pstride = (size_t)CHT * NCH;
  for (int p = 0; p < 5; ++p) {
    f32x4 acc[4][2];
#pragma unroll
    for (int i = 0; i < 4; ++i)
#pragma unroll
      for (int j = 0; j < 2; ++j) acc[i][j] = (f32x4){0.f, 0.f, 0.f, 0.f};

#pragma unroll 2
    for (int kt = 0; kt < 4; ++kt) {
#pragma unroll
      for (int h = 0; h < 2; ++h) {
        // B fragments: wave-contiguous 1KB from fragment-ordered Wt
        int grp = (((p * 4 + ct) * 4 + kt) * 2 + h) * 4 + wc;
        const u16* wp = Wt + (size_t)grp * 1024 + lane * 8;
        bf16x8 bfr[2];
        bfr[0] = *(const bf16x8*)wp;
        bfr[1] = *(const bf16x8*)(wp + 512);
        const int kb = kt * 8 + h * 4 + l4;
        bf16x8 af[4];
#pragma unroll
        for (int i = 0; i < 4; ++i)
          af[i] = *(const bf16x8*)(
              As + (size_t)(kb * 64 + i * 16 + l15) * 8);
#pragma unroll
        for (int i = 0; i < 4; ++i)
#pragma unroll
          for (int j = 0; j < 2; ++j)
            acc[i][j] = __builtin_amdgcn_mfma_f32_16x16x32_bf16(
                af[i], bfr[j], acc[i][j], 0, 0, 0);
      }
    }

    // epilogue
    u16* pl = buf + (size_t)p * pstride;
#pragma unroll
    for (int j = 0; j < 2; ++j) {
      int ch2 = ch0 + wc * 32 + j * 16 + l15;
      float bv = (p >= 3) ? bias[p * 512 + ch2] : 0.f;
#pragma unroll
      for (int i = 0; i < 4; ++i) {
        int tl = rt * 4 + i;
        int tf = t0c + tl;
        bool rec = (p == 1) && ((tf & 31) == 31);
#pragma unroll
        for (int r = 0; r < 4; r += 2) {
          float va = acc[i][j][r], vb = acc[i][j][r + 1];
          if (p >= 3) {
            va = 1.f / (1.f + __expf(-(va + bv)));
            vb = 1.f / (1.f + __expf(-(vb + bv)));
          }
          u32 pk = cvtpk(va, vb);
          int b = l4 * 4 + r;             // row&15 = batch
          int ch = b * 512 + ch2;
          size_t o = (size_t)tl * NCH + ch;
          pl[o] = (u16)pk;
          pl[o + 512] = (u16)(pk >> 16);  // b+1 -> ch+512
          if (rec) {
            size_t xo = (size_t)(tf >> 5) * NCH + ch;
            X2B[xo] = (u16)pk;
            X2B[xo + 512] = (u16)(pk >> 16);
          }
        }
      }
    }
  }
}

// -------------------------------------------------------------------------
// Pass A (per chunk): per (channel, segment) affine summary. 4 ch/thread:
// 8B loads, (CHT/32)*8 blocks -> 8 waves/CU, unroll 8 for load pipelining.
__global__ __launch_bounds__(256) void scanA_kernel(
    const u16* __restrict__ buf, const float* __restrict__ d_init,
    const u16* __restrict__ X2B,
    float* __restrict__ A1, float* __restrict__ B1,
    float* __restrict__ A2, float* __restrict__ B2, int c, int CHT) {
  int bid = blockIdx.x;               // (CHT/32) * 8 blocks
  int sl = bid >> 3, chb = bid & 7;
  int ch = chb * 1024 + threadIdx.x * 4;
  int s = c * (CHT / 32) + sl;        // global segment
  size_t pstride = (size_t)CHT * NCH;
  const u16* p0 = buf + (size_t)(sl * 32) * NCH + ch;

  float x2p[4];
  if (s == 0) {
    f32x4 d0 = *(const f32x4*)(d_init + ch);
#pragma unroll
    for (int r = 0; r < 4; ++r) x2p[r] = d0[r];
  } else {
    union { bf16x4v v; u16 s[4]; } xv;
    xv.v = *(const bf16x4v*)(X2B + (size_t)(s - 1) * NCH + ch);
#pragma unroll
    for (int r = 0; r < 4; ++r) x2p[r] = bf2f(xv.s[r]);
  }

  float a1[4], b1[4], a2[4], b2[4];
#pragma unroll
  for (int r = 0; r < 4; ++r) { a1[r] = 1.f; b1[r] = 0.f; a2[r] = 1.f; b2[r] = 0.f; }

#pragma unroll 8
  for (int tt = 0; tt < SEGLEN; ++tt) {
    size_t off = (size_t)tt * NCH;
    union U { bf16x4v v; u16 s[4]; } v0, v1, v2, v3, v4;
    v0.v = *(const bf16x4v*)(p0 + off);
    v1.v = *(const bf16x4v*)(p0 + pstride + off);
    v2.v = *(const bf16x4v*)(p0 + 2 * pstride + off);
    v3.v = *(const bf16x4v*)(p0 + 3 * pstride + off);
    v4.v = *(const bf16x4v*)(p0 + 4 * pstride + off);
#pragma unroll
    for (int r = 0; r < 4; ++r) {
      float x1 = bf2f(v0.s[r]), x2 = bf2f(v1.s[r]), x3 = bf2f(v2.s[r]);
      float f1 = bf2f(v3.s[r]), f2 = bf2f(v4.s[r]);
      a1[r] *= f1; b1[r] = f1 * b1[r] + (1.f - f1) * x1;
      float tmp = x3 * x2p[r];
      a2[r] *= f2; b2[r] = f2 * b2[r] + (1.f - f2) * tmp;
      x2p[r] = x2;
    }
  }
  size_t o = (size_t)s * NCH + ch;
  *(f32x4*)(A1 + o) = (f32x4){a1[0], a1[1], a1[2], a1[3]};
  *(f32x4*)(B1 + o) = (f32x4){b1[0], b1[1], b1[2], b1[3]};
  *(f32x4*)(A2 + o) = (f32x4){a2[0], a2[1], a2[2], a2[3]};
  *(f32x4*)(B2 + o) = (f32x4){b2[0], b2[1], b2[2], b2[3]};
}

// -------------------------------------------------------------------------
// Pass B: compose the 64 segment maps per channel -> carry-in per segment,
// plus final states (c1_f, c2_f, d_f) directly into out (f32).
__global__ __launch_bounds__(256) void scanB_kernel(
    const float* __restrict__ A1, const float* __restrict__ B1,
    const float* __restrict__ A2, const float* __restrict__ B2,
    const float* __restrict__ c1_init, const float* __restrict__ c2_init,
    const u16* __restrict__ X2B,
    float* __restrict__ C1c, float* __restrict__ C2c, float* __restrict__ out) {
  int ch = blockIdx.x * 256 + threadIdx.x;  // < 8192
  float c1 = c1_init[ch], c2 = c2_init[ch];
#pragma unroll 8
  for (int s = 0; s < SEGS; ++s) {
    int o = s * NCH + ch;
    C1c[o] = c1; C2c[o] = c2;
    c1 = A1[o] * c1 + B1[o];
    c2 = A2[o] * c2 + B2[o];
  }
  out[OFF_C1F + ch] = c1;
  out[OFF_C2F + ch] = c2;
  // d_f = x2 (flipped domain) at t = 2047 = segment-boundary slot 63
  out[OFF_DF + ch] = bf2f(X2B[(size_t)63 * NCH + ch]);
}

// -------------------------------------------------------------------------
// Pass C (per chunk): replay with known carries, write c1s/c2s as f32
// (un-flip dir=1 on store). 4 ch/thread, nontemporal output stores.
__global__ __launch_bounds__(256) void scanC_kernel(
    const u16* __restrict__ buf, const float* __restrict__ d_init,
    const u16* __restrict__ X2B,
    const float* __restrict__ C1c, const float* __restrict__ C2c,
    float* __restrict__ out, int c, int CHT) {
  int bid = blockIdx.x;               // (CHT/32) * 8 blocks
  int sl = bid >> 3, chb = bid & 7;
  int ch = chb * 1024 + threadIdx.x * 4;
  int s = c * (CHT / 32) + sl;
  size_t pstride = (size_t)CHT * NCH;
  const u16* p0 = buf + (size_t)(sl * 32) * NCH + ch;
  int dir = (ch >> 8) & 1;            // uniform across the thread's 4 channels

  float x2p[4];
  if (s == 0) {
    f32x4 d0 = *(const f32x4*)(d_init + ch);
#pragma unroll
    for (int r = 0; r < 4; ++r) x2p[r] = d0[r];
  } else {
    union { bf16x4v v; u16 s[4]; } xv;
    xv.v = *(const bf16x4v*)(X2B + (size_t)(s - 1) * NCH + ch);
#pragma unroll
    for (int r = 0; r < 4; ++r) x2p[r] = bf2f(xv.s[r]);
  }

  float c1[4], c2[4];
  {
    size_t o = (size_t)s * NCH + ch;
    f32x4 u0 = *(const f32x4*)(C1c + o);
    f32x4 w0 = *(const f32x4*)(C2c + o);
#pragma unroll
    for (int r = 0; r < 4; ++r) { c1[r] = u0[r]; c2[r] = w0[r]; }
  }

#pragma unroll 8
  for (int tt = 0; tt < SEGLEN; ++tt) {
    size_t off = (size_t)tt * NCH;
    union U { bf16x4v v; u16 s[4]; } v0, v1, v2, v3, v4;
    v0.v = *(const bf16x4v*)(p0 + off);
    v1.v = *(const bf16x4v*)(p0 + pstride + off);
    v2.v = *(const bf16x4v*)(p0 + 2 * pstride + off);
    v3.v = *(const bf16x4v*)(p0 + 3 * pstride + off);
    v4.v = *(const bf16x4v*)(p0 + 4 * pstride + off);
#pragma unroll
    for (int r = 0; r < 4; ++r) {
      float x1 = bf2f(v0.s[r]), x2 = bf2f(v1.s[r]), x3 = bf2f(v2.s[r]);
      float f1 = bf2f(v3.s[r]), f2 = bf2f(v4.s[r]);
      c1[r] = f1 * c1[r] + (1.f - f1) * x1;
      float tmp = x3 * x2p[r];
      c2[r] = f2 * c2[r] + (1.f - f2) * tmp;
      x2p[r] = x2;
    }
    int tfl = s * 32 + tt;
    int t_out = dir ? (SL - 1 - tfl) : tfl;
    float* o1 = out + (size_t)t_out * NCH + ch;
    f32x4 s1 = (f32x4){c1[0], c1[1], c1[2], c1[3]};
    f32x4 s2 = (f32x4){c2[0], c2[1], c2[2], c2[3]};
    __builtin_nontemporal_store(s1, (f32x4*)o1);
    __builtin_nontemporal_store(s2, (f32x4*)(o1 + OFF_C2S));
  }
}

// -------------------------------------------------------------------------
extern "C" void kernel_launch(void* const* d_in, const int* in_sizes, int n_in,
                              void* d_out, int out_size, void* d_ws, size_t ws_size,
                              hipStream_t stream) {
  const float* x    = (const float*)d_in[0];   // (2048,16,256) f32
  const float* W    = (const float*)d_in[1];   // (256,3072) f32
  const float* bias = (const float*)d_in[2];   // (3072,) f32
  const float* c1i  = (const float*)d_in[3];   // (16,512) f32
  const float* c2i  = (const float*)d_in[4];
  const float* di   = (const float*)d_in[5];
  float* out = (float*)d_out;                  // f32 output (ref dtype)

  uint8_t* w8 = (uint8_t*)d_ws;
  u16* Wt  = (u16*)w8;                              // 1,310,720 B
  u16* X2B = (u16*)(w8 + 1310720ull);               // 1,048,576 B
  float* A1  = (float*)(w8 + 2359296ull);           // 6 x 2,097,152 B
  float* B1  = A1 + SEGS * NCH;
  float* A2  = B1 + SEGS * NCH;
  float* B2  = A2 + SEGS * NCH;
  float* C1c = B2 + SEGS * NCH;
  float* C2c = C1c + SEGS * NCH;
  const size_t FIXED = 2359296ull + 6ull * 2097152ull;  // 14,942,208 B
  u16* buf = (u16*)(w8 + FIXED);

  // pick the least chunking that fits ws_size (call-invariant)
  int NCHUNK = 64;
  size_t avail = (ws_size > FIXED) ? (ws_size - FIXED) : 0;
  for (int nc = 1; nc <= 64; nc <<= 1) {
    size_t need = (size_t)5 * (SL / nc) * NCH * 2;
    if (need <= avail) { NCHUNK = nc; break; }
  }
  const int CHT = SL / NCHUNK;

  hipLaunchKernelGGL(repack_kernel, dim3(2560), dim3(256), 0, stream, W, Wt);
  for (int c = 0; c < NCHUNK; ++c) {
    hipLaunchKernelGGL(gemm_kernel, dim3(CHT / 4, 4), dim3(256), 0, stream,
                       x, Wt, bias, buf, X2B, c * CHT, CHT);
    hipLaunchKernelGGL(scanA_kernel, dim3((CHT / 32) * 8), dim3(256), 0, stream,
                       buf, di, X2B, A1, B1, A2, B2, c, CHT);
  }
  hipLaunchKernelGGL(scanB_kernel, dim3(32), dim3(256), 0, stream,
                     A1, B1, A2, B2, c1i, c2i, X2B, C1c, C2c, out);
  for (int c = 0; c < NCHUNK; ++c) {
    if (NCHUNK > 1)
      hipLaunchKernelGGL(gemm_kernel, dim3(CHT / 4, 4), dim3(256), 0, stream,
                         x, Wt, bias, buf, X2B, c * CHT, CHT);
    hipLaunchKernelGGL(scanC_kernel, dim3((CHT / 32) * 8), dim3(256), 0, stream,
                       buf, di, X2B, C1c, C2c, out, c, CHT);
  }
}